// Round 4
// baseline (1150.209 us; speedup 1.0000x reference)
//
#include <hip/hip_runtime.h>
#include <hip/hip_bf16.h>

#define D 128
#define NBINS 157    // ceil(10000/64) bins of 64 nodes (dst >> 6)
#define BIN_CAP 4608 // mean 4076 + ~8 sigma headroom
#define EPB 4096     // edges per bin_scatter block (512 thr x 8)

__global__ void zero_bins(int* binTotal) {
    if (threadIdx.x < NBINS) binTotal[threadIdx.x] = 0;
}

// ---------- pass 1: bin edges by dst>>6, LDS-staged coalesced writes ----------
__global__ __launch_bounds__(512) void bin_scatter(const int* __restrict__ src,
                                                   const int* __restrict__ dst,
                                                   int* __restrict__ binTotal,
                                                   int* __restrict__ binned, int E) {
    __shared__ int cnt[NBINS];
    __shared__ int loff[NBINS];
    __shared__ int gbase[NBINS];
    __shared__ int scur[NBINS];
    __shared__ int stage[EPB];
    int tid = threadIdx.x;
    for (int b = tid; b < NBINS; b += 512) cnt[b] = 0;
    __syncthreads();

    int base = blockIdx.x * EPB + tid * 8;
    int s[8], dl[8], bn[8];
    int ne = 0;
    if (base + 8 <= E) {
        const int4* s4 = (const int4*)(src + base);
        const int4* d4 = (const int4*)(dst + base);
        int4 a0 = s4[0], a1 = s4[1], c0 = d4[0], c1 = d4[1];
        int ss[8] = {a0.x, a0.y, a0.z, a0.w, a1.x, a1.y, a1.z, a1.w};
        int dd[8] = {c0.x, c0.y, c0.z, c0.w, c1.x, c1.y, c1.z, c1.w};
        ne = 8;
        #pragma unroll
        for (int i = 0; i < 8; ++i) { s[i] = ss[i]; bn[i] = dd[i] >> 6; dl[i] = dd[i] & 63; }
    } else {
        for (int i = 0; i < 8; ++i) {
            int e = base + i;
            if (e < E) { s[ne] = src[e]; int d = dst[e]; bn[ne] = d >> 6; dl[ne] = d & 63; ++ne; }
        }
    }
    for (int i = 0; i < ne; ++i) atomicAdd(&cnt[bn[i]], 1);
    __syncthreads();

    // global space reservation (one atomic per bin per block) + local exclusive scan
    if (tid < NBINS) gbase[tid] = atomicAdd(&binTotal[tid], cnt[tid]);
    if (tid < 64) {
        int c0 = (3 * tid     < NBINS) ? cnt[3 * tid    ] : 0;
        int c1 = (3 * tid + 1 < NBINS) ? cnt[3 * tid + 1] : 0;
        int c2 = (3 * tid + 2 < NBINS) ? cnt[3 * tid + 2] : 0;
        int tsum = c0 + c1 + c2;
        int incl = tsum;
        #pragma unroll
        for (int off = 1; off < 64; off <<= 1) {
            int t = __shfl_up(incl, off);
            if (tid >= off) incl += t;
        }
        int excl = incl - tsum;
        if (3 * tid     < NBINS) loff[3 * tid    ] = excl;
        if (3 * tid + 1 < NBINS) loff[3 * tid + 1] = excl + c0;
        if (3 * tid + 2 < NBINS) loff[3 * tid + 2] = excl + c0 + c1;
    }
    __syncthreads();
    if (tid < NBINS) scur[tid] = loff[tid];
    __syncthreads();

    // scatter into LDS stage, packed src | dstLocal<<14  (src < 16384)
    for (int i = 0; i < ne; ++i) {
        int p = atomicAdd(&scur[bn[i]], 1);
        stage[p] = s[i] | (dl[i] << 14);
    }
    __syncthreads();

    // coalesced run copy-out
    int wv = tid >> 6, lane = tid & 63;
    for (int b = wv; b < NBINS; b += 8) {
        int n = cnt[b], so = loff[b], go = b * BIN_CAP + gbase[b];
        for (int i = lane; i < n; i += 64) binned[go + i] = stage[so + i];
    }
}

// ---------- degrees + dinv per bin (wave-replicated 64-ctr histogram) ----------
__global__ __launch_bounds__(256) void bin_hist(const int* __restrict__ binTotal,
                                                const int* __restrict__ binned,
                                                float* __restrict__ dinv, int N) {
    __shared__ int h[4][64];
    int b = blockIdx.x, tid = threadIdx.x;
    int wv = tid >> 6, lane = tid & 63;
    h[wv][lane] = 0;
    __syncthreads();
    int cntb = binTotal[b];
    const int* bp = binned + b * BIN_CAP;
    for (int i = tid; i < cntb; i += 256) atomicAdd(&h[wv][bp[i] >> 14], 1);
    __syncthreads();
    if (tid < 64) {
        int deg = h[0][tid] + h[1][tid] + h[2][tid] + h[3][tid];
        int node = b * 64 + tid;
        if (node < N) dinv[node] = rsqrtf((float)(deg + 1));  // +1 self loop
    }
}

// ---------- GEMM: Z[row] = (X[row] @ W) * dinv[row] ----------
__global__ __launch_bounds__(256) void gemm_scale(const float* __restrict__ X,
                                                  const float* __restrict__ W,
                                                  const float* __restrict__ dinv,
                                                  float* __restrict__ Z, int N) {
    __shared__ float Ws[D * D];
    {
        const float4* W4 = (const float4*)W;
        float4* Ws4 = (float4*)Ws;
        #pragma unroll
        for (int i = 0; i < 16; ++i)
            Ws4[threadIdx.x + 256 * i] = W4[threadIdx.x + 256 * i];
    }
    __syncthreads();
    const float2* Ws2 = (const float2*)Ws;
    int col2 = threadIdx.x & 63;
    int wv   = __builtin_amdgcn_readfirstlane(threadIdx.x >> 6);
    int row0 = blockIdx.x * 16 + wv * 4;
    if (row0 >= N) return;

    const float4* xr[4];
    #pragma unroll
    for (int r = 0; r < 4; ++r) {
        int rr = row0 + r; if (rr > N - 1) rr = N - 1;
        xr[r] = (const float4*)(X + (size_t)rr * D);
    }
    float accx[4] = {0.f, 0.f, 0.f, 0.f};
    float accy[4] = {0.f, 0.f, 0.f, 0.f};
    #pragma unroll 8
    for (int kb = 0; kb < 32; ++kb) {
        float4 xv[4];
        #pragma unroll
        for (int r = 0; r < 4; ++r) xv[r] = xr[r][kb];
        #pragma unroll
        for (int kk = 0; kk < 4; ++kk) {
            float2 w = Ws2[(4 * kb + kk) * 64 + col2];
            #pragma unroll
            for (int r = 0; r < 4; ++r) {
                float xs = ((const float*)&xv[r])[kk];
                accx[r] = fmaf(xs, w.x, accx[r]);
                accy[r] = fmaf(xs, w.y, accy[r]);
            }
        }
    }
    #pragma unroll
    for (int r = 0; r < 4; ++r) {
        int rr = row0 + r;
        if (rr < N) {
            float dv = dinv[rr];
            ((float2*)Z)[(size_t)rr * 64 + col2] = make_float2(accx[r] * dv, accy[r] * dv);
        }
    }
}

// ---------- bin-centric aggregation over UNSORTED bins ----------
// block = (bin, slice of 32 floats). LDS acc[64 nodes][33] (pad -> bank spread).
// 8 edge-groups x 8 lanes per wave; ds_add_f32 accumulate; gather = 128B/edge.
__global__ __launch_bounds__(256) void aggregate_bin(const float* __restrict__ Z,
                                                     const int* __restrict__ binTotal,
                                                     const int* __restrict__ binned,
                                                     const float* __restrict__ dinv,
                                                     const float* __restrict__ bias,
                                                     float* __restrict__ Out, int N) {
    __shared__ float acc[64 * 33];
    int tid = threadIdx.x;
    int b = blockIdx.x >> 2;
    int s = blockIdx.x & 3;
    for (int i = tid; i < 64 * 33; i += 256) acc[i] = 0.f;
    __syncthreads();

    int cntb = binTotal[b];
    const int* bp = binned + b * BIN_CAP;
    int wv = tid >> 6, lane = tid & 63;
    int g = lane >> 3, l8 = lane & 7;
    const float4* Z4 = (const float4*)Z;
    int sliceBase = s * 8 + l8;              // float4 slot within 32-float4 row

    for (int e0 = wv * 64; e0 < cntb; e0 += 256) {
        int cnt = cntb - e0; if (cnt > 64) cnt = 64;
        int my = (lane < cnt) ? bp[e0 + lane] : 0;
        int rounds = cnt >> 3;
        for (int r = 0; r < rounds; ++r) {
            int pk = __shfl(my, r * 8 + g);
            int srcRow = pk & 0x3FFF;
            int dl = pk >> 14;
            float4 v = Z4[srcRow * 32 + sliceBase];
            float* a = &acc[dl * 33 + l8 * 4];
            atomicAdd(a + 0, v.x); atomicAdd(a + 1, v.y);
            atomicAdd(a + 2, v.z); atomicAdd(a + 3, v.w);
        }
        int rem = cnt & 7;
        if (rem) {
            int ei = rounds * 8 + g;
            int pk = __shfl(my, ei < cnt ? ei : 0);
            if (g < rem) {
                int srcRow = pk & 0x3FFF;
                int dl = pk >> 14;
                float4 v = Z4[srcRow * 32 + sliceBase];
                float* a = &acc[dl * 33 + l8 * 4];
                atomicAdd(a + 0, v.x); atomicAdd(a + 1, v.y);
                atomicAdd(a + 2, v.z); atomicAdd(a + 3, v.w);
            }
        }
    }
    __syncthreads();

    // writeout: out[n] = (acc + Zself)*dinv[n] + bias  (coalesced per node-slice)
    for (int f = tid; f < 64 * 32; f += 256) {
        int nl = f >> 5, j = f & 31;
        int node = b * 64 + nl;
        if (node < N) {
            float selfv = Z[node * D + s * 32 + j];
            float dv = dinv[node];
            float bv = bias[s * 32 + j];
            Out[node * D + s * 32 + j] = (acc[nl * 33 + j] + selfv) * dv + bv;
        }
    }
}

extern "C" void kernel_launch(void* const* d_in, const int* in_sizes, int n_in,
                              void* d_out, int out_size, void* d_ws, size_t ws_size,
                              hipStream_t stream) {
    const float* X  = (const float*)d_in[0];
    const int*   ed = (const int*)d_in[1];
    const float* W1 = (const float*)d_in[2];
    const float* b1 = (const float*)d_in[3];
    const float* W2 = (const float*)d_in[4];
    const float* b2 = (const float*)d_in[5];
    float* out = (float*)d_out;

    const int N = in_sizes[0] / D;       // 10000
    const int E = in_sizes[1] / 2;       // 640000
    const int* src = ed;
    const int* dst = ed + E;

    char* w = (char*)d_ws;
    float* Z        = (float*)w;   w += (size_t)N * D * sizeof(float);
    int*   binned   = (int*)w;     w += (size_t)NBINS * BIN_CAP * sizeof(int);
    float* dinv     = (float*)w;   w += (size_t)N * sizeof(float);
    int*   binTotal = (int*)w;     w += (size_t)NBINS * sizeof(int);

    zero_bins<<<1, 256, 0, stream>>>(binTotal);
    bin_scatter<<<(E + EPB - 1) / EPB, 512, 0, stream>>>(src, dst, binTotal, binned, E);
    bin_hist<<<NBINS, 256, 0, stream>>>(binTotal, binned, dinv, N);

    int gGemm = (N + 15) / 16;
    int gAgg  = NBINS * 4;

    gemm_scale<<<gGemm, 256, 0, stream>>>(X, W1, dinv, Z, N);
    aggregate_bin<<<gAgg, 256, 0, stream>>>(Z, binTotal, binned, dinv, b1, out, N);

    gemm_scale<<<gGemm, 256, 0, stream>>>(out, W2, dinv, Z, N);
    aggregate_bin<<<gAgg, 256, 0, stream>>>(Z, binTotal, binned, dinv, b2, out, N);
}

// Round 5
// 164.015 us; speedup vs baseline: 7.0128x; 7.0128x over previous
//
#include <hip/hip_runtime.h>
#include <hip/hip_bf16.h>

#define D 128
#define NBINS 157    // ceil(10000/64) bins of 64 nodes (dst >> 6)
#define BIN_CAP 4608 // mean 4076 + ~8 sigma headroom
#define EPB 4096     // edges per bin_scatter block (512 thr x 8)

__global__ void zero_bins(int* binTotal) {
    if (threadIdx.x < NBINS) binTotal[threadIdx.x] = 0;
}

// ---------- pass 1: bin edges by dst>>6, LDS-staged coalesced writes ----------
__global__ __launch_bounds__(512) void bin_scatter(const int* __restrict__ src,
                                                   const int* __restrict__ dst,
                                                   int* __restrict__ binTotal,
                                                   int* __restrict__ binned, int E) {
    __shared__ int cnt[NBINS];
    __shared__ int loff[NBINS];
    __shared__ int gbase[NBINS];
    __shared__ int scur[NBINS];
    __shared__ int stage[EPB];
    int tid = threadIdx.x;
    for (int b = tid; b < NBINS; b += 512) cnt[b] = 0;
    __syncthreads();

    int base = blockIdx.x * EPB + tid * 8;
    int s[8], dl[8], bn[8];
    int ne = 0;
    if (base + 8 <= E) {
        const int4* s4 = (const int4*)(src + base);
        const int4* d4 = (const int4*)(dst + base);
        int4 a0 = s4[0], a1 = s4[1], c0 = d4[0], c1 = d4[1];
        int ss[8] = {a0.x, a0.y, a0.z, a0.w, a1.x, a1.y, a1.z, a1.w};
        int dd[8] = {c0.x, c0.y, c0.z, c0.w, c1.x, c1.y, c1.z, c1.w};
        ne = 8;
        #pragma unroll
        for (int i = 0; i < 8; ++i) { s[i] = ss[i]; bn[i] = dd[i] >> 6; dl[i] = dd[i] & 63; }
    } else {
        for (int i = 0; i < 8; ++i) {
            int e = base + i;
            if (e < E) { s[ne] = src[e]; int d = dst[e]; bn[ne] = d >> 6; dl[ne] = d & 63; ++ne; }
        }
    }
    for (int i = 0; i < ne; ++i) atomicAdd(&cnt[bn[i]], 1);   // int LDS atomic: native ds_add
    __syncthreads();

    // global space reservation (one atomic per bin per block) + local exclusive scan
    if (tid < NBINS) gbase[tid] = atomicAdd(&binTotal[tid], cnt[tid]);
    if (tid < 64) {
        int c0 = (3 * tid     < NBINS) ? cnt[3 * tid    ] : 0;
        int c1 = (3 * tid + 1 < NBINS) ? cnt[3 * tid + 1] : 0;
        int c2 = (3 * tid + 2 < NBINS) ? cnt[3 * tid + 2] : 0;
        int tsum = c0 + c1 + c2;
        int incl = tsum;
        #pragma unroll
        for (int off = 1; off < 64; off <<= 1) {
            int t = __shfl_up(incl, off);
            if (tid >= off) incl += t;
        }
        int excl = incl - tsum;
        if (3 * tid     < NBINS) loff[3 * tid    ] = excl;
        if (3 * tid + 1 < NBINS) loff[3 * tid + 1] = excl + c0;
        if (3 * tid + 2 < NBINS) loff[3 * tid + 2] = excl + c0 + c1;
    }
    __syncthreads();
    if (tid < NBINS) scur[tid] = loff[tid];
    __syncthreads();

    // scatter into LDS stage, packed src | dstLocal<<14  (src < 16384)
    for (int i = 0; i < ne; ++i) {
        int p = atomicAdd(&scur[bn[i]], 1);
        stage[p] = s[i] | (dl[i] << 14);
    }
    __syncthreads();

    // coalesced run copy-out
    int wv = tid >> 6, lane = tid & 63;
    for (int b = wv; b < NBINS; b += 8) {
        int n = cnt[b], so = loff[b], go = b * BIN_CAP + gbase[b];
        for (int i = lane; i < n; i += 64) binned[go + i] = stage[so + i];
    }
}

// ---------- pass 2: in-bin counting sort by dstLocal (per-wave hist+cursor) ----------
__global__ __launch_bounds__(256) void sort_bins(const int* __restrict__ binTotal,
                                                 int* __restrict__ binned,
                                                 float* __restrict__ dinv,
                                                 int* __restrict__ nodeStart,
                                                 int* __restrict__ nodeEnd, int N) {
    __shared__ int h[4][64];
    __shared__ int cur[4][64];
    __shared__ int stage[BIN_CAP];
    int b = blockIdx.x, tid = threadIdx.x;
    int wv = tid >> 6, lane = tid & 63;
    int cntb = binTotal[b];
    h[wv][lane] = 0;
    __syncthreads();
    const int* bp = binned + b * BIN_CAP;
    for (int i = tid; i < cntb; i += 256) atomicAdd(&h[wv][bp[i] >> 14], 1);
    __syncthreads();
    if (tid < 64) {
        int d0 = h[0][tid], d1 = h[1][tid], d2 = h[2][tid], d3 = h[3][tid];
        int deg = d0 + d1 + d2 + d3;
        int incl = deg;
        #pragma unroll
        for (int off = 1; off < 64; off <<= 1) {
            int t = __shfl_up(incl, off);
            if (tid >= off) incl += t;
        }
        int excl = incl - deg;
        cur[0][tid] = excl;
        cur[1][tid] = excl + d0;
        cur[2][tid] = excl + d0 + d1;
        cur[3][tid] = excl + d0 + d1 + d2;
        int node = b * 64 + tid;
        if (node < N) {
            dinv[node]      = rsqrtf((float)(deg + 1));   // +1 self loop
            nodeStart[node] = b * BIN_CAP + excl;
            nodeEnd[node]   = b * BIN_CAP + excl + deg;
        }
    }
    __syncthreads();
    for (int i = tid; i < cntb; i += 256) {
        int p = bp[i];
        int pos = atomicAdd(&cur[wv][p >> 14], 1);   // per-wave cursor: 4x less contention
        stage[pos] = p & 0x3FFF;
    }
    __syncthreads();
    int* bw = binned + b * BIN_CAP;
    for (int i = tid; i < cntb; i += 256) bw[i] = stage[i];
}

// ---------- GEMM: Z[row] = (X[row] @ W) * dinv[row] ----------
__global__ __launch_bounds__(256) void gemm_scale(const float* __restrict__ X,
                                                  const float* __restrict__ W,
                                                  const float* __restrict__ dinv,
                                                  float* __restrict__ Z, int N) {
    __shared__ float Ws[D * D];
    {
        const float4* W4 = (const float4*)W;
        float4* Ws4 = (float4*)Ws;
        #pragma unroll
        for (int i = 0; i < 16; ++i)
            Ws4[threadIdx.x + 256 * i] = W4[threadIdx.x + 256 * i];
    }
    __syncthreads();
    const float2* Ws2 = (const float2*)Ws;
    int col2 = threadIdx.x & 63;
    int wv   = __builtin_amdgcn_readfirstlane(threadIdx.x >> 6);
    int row0 = blockIdx.x * 16 + wv * 4;
    if (row0 >= N) return;

    const float4* xr[4];
    #pragma unroll
    for (int r = 0; r < 4; ++r) {
        int rr = row0 + r; if (rr > N - 1) rr = N - 1;
        xr[r] = (const float4*)(X + (size_t)rr * D);
    }
    float accx[4] = {0.f, 0.f, 0.f, 0.f};
    float accy[4] = {0.f, 0.f, 0.f, 0.f};
    #pragma unroll 8
    for (int kb = 0; kb < 32; ++kb) {
        float4 xv[4];
        #pragma unroll
        for (int r = 0; r < 4; ++r) xv[r] = xr[r][kb];
        #pragma unroll
        for (int kk = 0; kk < 4; ++kk) {
            float2 w = Ws2[(4 * kb + kk) * 64 + col2];
            #pragma unroll
            for (int r = 0; r < 4; ++r) {
                float xs = ((const float*)&xv[r])[kk];
                accx[r] = fmaf(xs, w.x, accx[r]);
                accy[r] = fmaf(xs, w.y, accy[r]);
            }
        }
    }
    #pragma unroll
    for (int r = 0; r < 4; ++r) {
        int rr = row0 + r;
        if (rr < N) {
            float dv = dinv[rr];
            ((float2*)Z)[(size_t)rr * 64 + col2] = make_float2(accx[r] * dv, accy[r] * dv);
        }
    }
}

// ---------- aggregation: XCD-sliced, float4 gathers, register accumulation ----------
// block = 4 waves = 4 nodes, slice = blockIdx&3 (128B of the row).
// Within a wave: 8 edge-groups x 8 lanes; each round = 1 KB gather (8 edges).
__global__ __launch_bounds__(256) void aggregate(const float* __restrict__ Z,
                                                 const int* __restrict__ nodeStart,
                                                 const int* __restrict__ nodeEnd,
                                                 const int* __restrict__ csr,
                                                 const float* __restrict__ dinv,
                                                 const float* __restrict__ bias,
                                                 float* __restrict__ Out, int N) {
    int s    = blockIdx.x & 3;
    int wv   = __builtin_amdgcn_readfirstlane(threadIdx.x >> 6);
    int node = (blockIdx.x >> 2) * 4 + wv;
    if (node >= N) return;
    int lane = threadIdx.x & 63;
    int grp  = lane >> 3;       // 0..7 edge sub-group
    int l8   = lane & 7;        // float4 slot within 128B slice
    int off4 = s * 8 + l8;

    const float4* Z4 = (const float4*)Z;
    float ax = 0.f, ay = 0.f, az = 0.f, aw = 0.f;
    int e   = nodeStart[node];
    int end = nodeEnd[node];
    while (e < end) {
        int cnt = end - e; if (cnt > 64) cnt = 64;
        int my = (lane < cnt) ? csr[e + lane] : 0;
        if (cnt == 64) {
            #pragma unroll
            for (int j = 0; j < 8; ++j) {
                int idx = __shfl(my, j * 8 + grp);
                float4 v = Z4[idx * 32 + off4];
                ax += v.x; ay += v.y; az += v.z; aw += v.w;
            }
        } else {
            int full = cnt >> 3;
            for (int j = 0; j < full; ++j) {
                int idx = __shfl(my, j * 8 + grp);
                float4 v = Z4[idx * 32 + off4];
                ax += v.x; ay += v.y; az += v.z; aw += v.w;
            }
            int rem = cnt & 7;
            if (rem) {
                int ei = full * 8 + grp;
                int idx = __shfl(my, ei < cnt ? ei : 0);
                float4 v = Z4[idx * 32 + off4];
                if (grp < rem) { ax += v.x; ay += v.y; az += v.z; aw += v.w; }
            }
        }
        e += cnt;
    }
    // reduce across the 8 edge-groups (lane bits 3..5)
    #pragma unroll
    for (int m = 8; m <= 32; m <<= 1) {
        ax += __shfl_xor(ax, m);
        ay += __shfl_xor(ay, m);
        az += __shfl_xor(az, m);
        aw += __shfl_xor(aw, m);
    }
    if (lane < 8) {
        float4 self = Z4[node * 32 + off4];
        float dv = dinv[node];
        float4 b4 = ((const float4*)bias)[off4];
        float4 o;
        o.x = (ax + self.x) * dv + b4.x;
        o.y = (ay + self.y) * dv + b4.y;
        o.z = (az + self.z) * dv + b4.z;
        o.w = (aw + self.w) * dv + b4.w;
        ((float4*)Out)[node * 32 + off4] = o;
    }
}

extern "C" void kernel_launch(void* const* d_in, const int* in_sizes, int n_in,
                              void* d_out, int out_size, void* d_ws, size_t ws_size,
                              hipStream_t stream) {
    const float* X  = (const float*)d_in[0];
    const int*   ed = (const int*)d_in[1];
    const float* W1 = (const float*)d_in[2];
    const float* b1 = (const float*)d_in[3];
    const float* W2 = (const float*)d_in[4];
    const float* b2 = (const float*)d_in[5];
    float* out = (float*)d_out;

    const int N = in_sizes[0] / D;       // 10000
    const int E = in_sizes[1] / 2;       // 640000
    const int* src = ed;
    const int* dst = ed + E;

    char* w = (char*)d_ws;
    float* Z         = (float*)w;   w += (size_t)N * D * sizeof(float);
    int*   binned    = (int*)w;     w += (size_t)NBINS * BIN_CAP * sizeof(int);
    float* dinv      = (float*)w;   w += (size_t)N * sizeof(float);
    int*   nodeStart = (int*)w;     w += (size_t)N * sizeof(int);
    int*   nodeEnd   = (int*)w;     w += (size_t)N * sizeof(int);
    int*   binTotal  = (int*)w;     w += (size_t)NBINS * sizeof(int);

    zero_bins<<<1, 256, 0, stream>>>(binTotal);
    bin_scatter<<<(E + EPB - 1) / EPB, 512, 0, stream>>>(src, dst, binTotal, binned, E);
    sort_bins<<<NBINS, 256, 0, stream>>>(binTotal, binned, dinv, nodeStart, nodeEnd, N);

    int gGemm = (N + 15) / 16;
    int gAgg  = ((N + 3) / 4) * 4;

    gemm_scale<<<gGemm, 256, 0, stream>>>(X, W1, dinv, Z, N);
    aggregate<<<gAgg, 256, 0, stream>>>(Z, nodeStart, nodeEnd, binned, dinv, b1, out, N);

    gemm_scale<<<gGemm, 256, 0, stream>>>(out, W2, dinv, Z, N);
    aggregate<<<gAgg, 256, 0, stream>>>(Z, nodeStart, nodeEnd, binned, dinv, b2, out, N);
}

// Round 6
// 155.004 us; speedup vs baseline: 7.4205x; 1.0581x over previous
//
#include <hip/hip_runtime.h>
#include <hip/hip_bf16.h>

#define D 128
#define NBINS 157    // ceil(10000/64) bins of 64 nodes (dst >> 6)
#define BIN_CAP 4608 // mean 4076 + ~8 sigma headroom
#define EPB 4096     // edges per scatter block (512 thr x 8)

// ---------- K1: fused [Y = X@W (unscaled)] + [bin_scatter] ----------
// blocks [0, gGemm): gemm path, 32 rows/block, 8 waves x 4 rows
// blocks [gGemm, gGemm+157): scatter path (identical to R5 bin_scatter)
__global__ __launch_bounds__(512) void fused_gemm_scatter(
        const float* __restrict__ X, const float* __restrict__ W,
        float* __restrict__ Y,
        const int* __restrict__ src, const int* __restrict__ dst,
        int* __restrict__ binTotal, int* __restrict__ binned,
        int E, int N, int gGemm) {
    __shared__ float smem[D * D];   // 64 KB, dual-purpose
    int tid = threadIdx.x;

    if ((int)blockIdx.x < gGemm) {
        // ---- GEMM path ----
        {
            const float4* W4 = (const float4*)W;
            float4* Ws4 = (float4*)smem;
            #pragma unroll
            for (int i = 0; i < 8; ++i)
                Ws4[tid + 512 * i] = W4[tid + 512 * i];
        }
        __syncthreads();
        const float2* Ws2 = (const float2*)smem;
        int col2 = tid & 63;
        int wv   = __builtin_amdgcn_readfirstlane(tid >> 6);   // 0..7
        int row0 = blockIdx.x * 32 + wv * 4;
        if (row0 >= N) return;

        const float4* xr[4];
        #pragma unroll
        for (int r = 0; r < 4; ++r) {
            int rr = row0 + r; if (rr > N - 1) rr = N - 1;
            xr[r] = (const float4*)(X + (size_t)rr * D);
        }
        float accx[4] = {0.f, 0.f, 0.f, 0.f};
        float accy[4] = {0.f, 0.f, 0.f, 0.f};
        #pragma unroll 8
        for (int kb = 0; kb < 32; ++kb) {
            float4 xv[4];
            #pragma unroll
            for (int r = 0; r < 4; ++r) xv[r] = xr[r][kb];
            #pragma unroll
            for (int kk = 0; kk < 4; ++kk) {
                float2 w = Ws2[(4 * kb + kk) * 64 + col2];
                #pragma unroll
                for (int r = 0; r < 4; ++r) {
                    float xs = ((const float*)&xv[r])[kk];
                    accx[r] = fmaf(xs, w.x, accx[r]);
                    accy[r] = fmaf(xs, w.y, accy[r]);
                }
            }
        }
        #pragma unroll
        for (int r = 0; r < 4; ++r) {
            int rr = row0 + r;
            if (rr < N)
                ((float2*)Y)[(size_t)rr * 64 + col2] = make_float2(accx[r], accy[r]);
        }
    } else {
        // ---- scatter path ----
        int* cnt   = (int*)smem;
        int* loff  = cnt + 160;
        int* gbase = cnt + 320;
        int* scur  = cnt + 480;
        int* stage = cnt + 640;      // 4096 ints
        for (int b = tid; b < NBINS; b += 512) cnt[b] = 0;
        __syncthreads();

        int bid = blockIdx.x - gGemm;
        int base = bid * EPB + tid * 8;
        int s[8], dl[8], bn[8];
        int ne = 0;
        if (base + 8 <= E) {
            const int4* s4 = (const int4*)(src + base);
            const int4* d4 = (const int4*)(dst + base);
            int4 a0 = s4[0], a1 = s4[1], c0 = d4[0], c1 = d4[1];
            int ss[8] = {a0.x, a0.y, a0.z, a0.w, a1.x, a1.y, a1.z, a1.w};
            int dd[8] = {c0.x, c0.y, c0.z, c0.w, c1.x, c1.y, c1.z, c1.w};
            ne = 8;
            #pragma unroll
            for (int i = 0; i < 8; ++i) { s[i] = ss[i]; bn[i] = dd[i] >> 6; dl[i] = dd[i] & 63; }
        } else {
            for (int i = 0; i < 8; ++i) {
                int e = base + i;
                if (e < E) { s[ne] = src[e]; int d = dst[e]; bn[ne] = d >> 6; dl[ne] = d & 63; ++ne; }
            }
        }
        for (int i = 0; i < ne; ++i) atomicAdd(&cnt[bn[i]], 1);   // native ds_add (int)
        __syncthreads();

        if (tid < NBINS) gbase[tid] = atomicAdd(&binTotal[tid], cnt[tid]);
        if (tid < 64) {
            int c0 = (3 * tid     < NBINS) ? cnt[3 * tid    ] : 0;
            int c1 = (3 * tid + 1 < NBINS) ? cnt[3 * tid + 1] : 0;
            int c2 = (3 * tid + 2 < NBINS) ? cnt[3 * tid + 2] : 0;
            int tsum = c0 + c1 + c2;
            int incl = tsum;
            #pragma unroll
            for (int off = 1; off < 64; off <<= 1) {
                int t = __shfl_up(incl, off);
                if (tid >= off) incl += t;
            }
            int excl = incl - tsum;
            if (3 * tid     < NBINS) loff[3 * tid    ] = excl;
            if (3 * tid + 1 < NBINS) loff[3 * tid + 1] = excl + c0;
            if (3 * tid + 2 < NBINS) loff[3 * tid + 2] = excl + c0 + c1;
        }
        __syncthreads();
        if (tid < NBINS) scur[tid] = loff[tid];
        __syncthreads();

        for (int i = 0; i < ne; ++i) {
            int p = atomicAdd(&scur[bn[i]], 1);
            stage[p] = s[i] | (dl[i] << 14);      // src | dstLocal<<14
        }
        __syncthreads();

        int wv = tid >> 6, lane = tid & 63;
        for (int b = wv; b < NBINS; b += 8) {
            int n = cnt[b], so = loff[b], go = b * BIN_CAP + gbase[b];
            for (int i = lane; i < n; i += 64) binned[go + i] = stage[so + i];
        }
    }
}

// ---------- K2: in-bin counting sort + dinv + in-place scale of Y rows ----------
__global__ __launch_bounds__(256) void sort_bins(const int* __restrict__ binTotal,
                                                 int* __restrict__ binned,
                                                 float* __restrict__ dinv,
                                                 int* __restrict__ nodeStart,
                                                 int* __restrict__ nodeEnd,
                                                 float* __restrict__ Y, int N) {
    __shared__ int h[4][64];
    __shared__ int cur[4][64];
    __shared__ float sdinv[64];
    __shared__ int stage[BIN_CAP];
    int b = blockIdx.x, tid = threadIdx.x;
    int wv = tid >> 6, lane = tid & 63;
    int cntb = binTotal[b];
    h[wv][lane] = 0;
    __syncthreads();
    const int* bp = binned + b * BIN_CAP;
    for (int i = tid; i < cntb; i += 256) atomicAdd(&h[wv][bp[i] >> 14], 1);
    __syncthreads();
    if (tid < 64) {
        int d0 = h[0][tid], d1 = h[1][tid], d2 = h[2][tid], d3 = h[3][tid];
        int deg = d0 + d1 + d2 + d3;
        int incl = deg;
        #pragma unroll
        for (int off = 1; off < 64; off <<= 1) {
            int t = __shfl_up(incl, off);
            if (tid >= off) incl += t;
        }
        int excl = incl - deg;
        cur[0][tid] = excl;
        cur[1][tid] = excl + d0;
        cur[2][tid] = excl + d0 + d1;
        cur[3][tid] = excl + d0 + d1 + d2;
        float dv = rsqrtf((float)(deg + 1));   // +1 self loop
        sdinv[tid] = dv;
        int node = b * 64 + tid;
        if (node < N) {
            dinv[node]      = dv;
            nodeStart[node] = b * BIN_CAP + excl;
            nodeEnd[node]   = b * BIN_CAP + excl + deg;
        }
    }
    __syncthreads();
    for (int i = tid; i < cntb; i += 256) {
        int p = bp[i];
        int pos = atomicAdd(&cur[wv][p >> 14], 1);
        stage[pos] = p & 0x3FFF;
    }
    // in-place scale: Z rows of this bin = Y rows * dinv (each row owned by this block)
    {
        float4* Y4 = (float4*)Y;
        #pragma unroll
        for (int i = 0; i < 8; ++i) {
            int idx = tid + 256 * i;            // 64 rows x 32 float4
            int row = idx >> 5, c = idx & 31;
            int node = b * 64 + row;
            if (node < N) {
                float4 v = Y4[(size_t)node * 32 + c];
                float dv = sdinv[row];
                v.x *= dv; v.y *= dv; v.z *= dv; v.w *= dv;
                Y4[(size_t)node * 32 + c] = v;
            }
        }
    }
    __syncthreads();
    int* bw = binned + b * BIN_CAP;
    for (int i = tid; i < cntb; i += 256) bw[i] = stage[i];
}

// ---------- GEMM (layer 2): Z[row] = (X[row] @ W) * dinv[row] ----------
__global__ __launch_bounds__(256) void gemm_scale(const float* __restrict__ X,
                                                  const float* __restrict__ W,
                                                  const float* __restrict__ dinv,
                                                  float* __restrict__ Z, int N) {
    __shared__ float Ws[D * D];
    {
        const float4* W4 = (const float4*)W;
        float4* Ws4 = (float4*)Ws;
        #pragma unroll
        for (int i = 0; i < 16; ++i)
            Ws4[threadIdx.x + 256 * i] = W4[threadIdx.x + 256 * i];
    }
    __syncthreads();
    const float2* Ws2 = (const float2*)Ws;
    int col2 = threadIdx.x & 63;
    int wv   = __builtin_amdgcn_readfirstlane(threadIdx.x >> 6);
    int row0 = blockIdx.x * 16 + wv * 4;
    if (row0 >= N) return;

    const float4* xr[4];
    #pragma unroll
    for (int r = 0; r < 4; ++r) {
        int rr = row0 + r; if (rr > N - 1) rr = N - 1;
        xr[r] = (const float4*)(X + (size_t)rr * D);
    }
    float accx[4] = {0.f, 0.f, 0.f, 0.f};
    float accy[4] = {0.f, 0.f, 0.f, 0.f};
    #pragma unroll 8
    for (int kb = 0; kb < 32; ++kb) {
        float4 xv[4];
        #pragma unroll
        for (int r = 0; r < 4; ++r) xv[r] = xr[r][kb];
        #pragma unroll
        for (int kk = 0; kk < 4; ++kk) {
            float2 w = Ws2[(4 * kb + kk) * 64 + col2];
            #pragma unroll
            for (int r = 0; r < 4; ++r) {
                float xs = ((const float*)&xv[r])[kk];
                accx[r] = fmaf(xs, w.x, accx[r]);
                accy[r] = fmaf(xs, w.y, accy[r]);
            }
        }
    }
    #pragma unroll
    for (int r = 0; r < 4; ++r) {
        int rr = row0 + r;
        if (rr < N) {
            float dv = dinv[rr];
            ((float2*)Z)[(size_t)rr * 64 + col2] = make_float2(accx[r] * dv, accy[r] * dv);
        }
    }
}

// ---------- aggregation: XCD-sliced, float4 gathers, register accumulation ----------
__global__ __launch_bounds__(256) void aggregate(const float* __restrict__ Z,
                                                 const int* __restrict__ nodeStart,
                                                 const int* __restrict__ nodeEnd,
                                                 const int* __restrict__ csr,
                                                 const float* __restrict__ dinv,
                                                 const float* __restrict__ bias,
                                                 float* __restrict__ Out, int N) {
    int s    = blockIdx.x & 3;
    int wv   = __builtin_amdgcn_readfirstlane(threadIdx.x >> 6);
    int node = (blockIdx.x >> 2) * 4 + wv;
    if (node >= N) return;
    int lane = threadIdx.x & 63;
    int grp  = lane >> 3;
    int l8   = lane & 7;
    int off4 = s * 8 + l8;

    const float4* Z4 = (const float4*)Z;
    float ax = 0.f, ay = 0.f, az = 0.f, aw = 0.f;
    int e   = nodeStart[node];
    int end = nodeEnd[node];
    while (e < end) {
        int cnt = end - e; if (cnt > 64) cnt = 64;
        int my = (lane < cnt) ? csr[e + lane] : 0;
        if (cnt == 64) {
            #pragma unroll
            for (int j = 0; j < 8; ++j) {
                int idx = __shfl(my, j * 8 + grp);
                float4 v = Z4[idx * 32 + off4];
                ax += v.x; ay += v.y; az += v.z; aw += v.w;
            }
        } else {
            int full = cnt >> 3;
            for (int j = 0; j < full; ++j) {
                int idx = __shfl(my, j * 8 + grp);
                float4 v = Z4[idx * 32 + off4];
                ax += v.x; ay += v.y; az += v.z; aw += v.w;
            }
            int rem = cnt & 7;
            if (rem) {
                int ei = full * 8 + grp;
                int idx = __shfl(my, ei < cnt ? ei : 0);
                float4 v = Z4[idx * 32 + off4];
                if (grp < rem) { ax += v.x; ay += v.y; az += v.z; aw += v.w; }
            }
        }
        e += cnt;
    }
    #pragma unroll
    for (int m = 8; m <= 32; m <<= 1) {
        ax += __shfl_xor(ax, m);
        ay += __shfl_xor(ay, m);
        az += __shfl_xor(az, m);
        aw += __shfl_xor(aw, m);
    }
    if (lane < 8) {
        float4 self = Z4[node * 32 + off4];
        float dv = dinv[node];
        float4 b4 = ((const float4*)bias)[off4];
        float4 o;
        o.x = (ax + self.x) * dv + b4.x;
        o.y = (ay + self.y) * dv + b4.y;
        o.z = (az + self.z) * dv + b4.z;
        o.w = (aw + self.w) * dv + b4.w;
        ((float4*)Out)[node * 32 + off4] = o;
    }
}

extern "C" void kernel_launch(void* const* d_in, const int* in_sizes, int n_in,
                              void* d_out, int out_size, void* d_ws, size_t ws_size,
                              hipStream_t stream) {
    const float* X  = (const float*)d_in[0];
    const int*   ed = (const int*)d_in[1];
    const float* W1 = (const float*)d_in[2];
    const float* b1 = (const float*)d_in[3];
    const float* W2 = (const float*)d_in[4];
    const float* b2 = (const float*)d_in[5];
    float* out = (float*)d_out;

    const int N = in_sizes[0] / D;       // 10000
    const int E = in_sizes[1] / 2;       // 640000
    const int* src = ed;
    const int* dst = ed + E;

    char* w = (char*)d_ws;
    float* Z         = (float*)w;   w += (size_t)N * D * sizeof(float);
    int*   binned    = (int*)w;     w += (size_t)NBINS * BIN_CAP * sizeof(int);
    float* dinv      = (float*)w;   w += (size_t)N * sizeof(float);
    int*   nodeStart = (int*)w;     w += (size_t)N * sizeof(int);
    int*   nodeEnd   = (int*)w;     w += (size_t)N * sizeof(int);
    int*   binTotal  = (int*)w;     w += (size_t)NBINS * sizeof(int);

    hipMemsetAsync(binTotal, 0, NBINS * sizeof(int), stream);

    int gGemm1 = (N + 31) / 32;                 // 313
    int gScat  = (E + EPB - 1) / EPB;           // 157
    fused_gemm_scatter<<<gGemm1 + gScat, 512, 0, stream>>>(
        X, W1, Z, src, dst, binTotal, binned, E, N, gGemm1);
    sort_bins<<<NBINS, 256, 0, stream>>>(binTotal, binned, dinv, nodeStart, nodeEnd, Z, N);

    int gAgg = ((N + 3) / 4) * 4;
    aggregate<<<gAgg, 256, 0, stream>>>(Z, nodeStart, nodeEnd, binned, dinv, b1, out, N);

    int gGemm2 = (N + 15) / 16;
    gemm_scale<<<gGemm2, 256, 0, stream>>>(out, W2, dinv, Z, N);
    aggregate<<<gAgg, 256, 0, stream>>>(Z, nodeStart, nodeEnd, binned, dinv, b2, out, N);
}